// Round 13
// baseline (148.372 us; speedup 1.0000x reference)
//
#include <hip/hip_runtime.h>
#include <hip/hip_fp16.h>
#include <math.h>

#define BB 2
#define CC 64
#define NN 4096
#define MM 256
#define KK 32
#define GG 4
#define EPSF 1e-5f

__device__ __forceinline__ float gelu_exact(float x) {
    return 0.5f * x * (1.0f + erff(x * 0.70710678118654752f));
}

__device__ __forceinline__ unsigned pkmax(unsigned a, unsigned b) {
    unsigned d;
    asm volatile("v_pk_max_f16 %0, %1, %2" : "=v"(d) : "v"(a), "v"(b));
    return d;
}
__device__ __forceinline__ unsigned pkmin(unsigned a, unsigned b) {
    unsigned d;
    asm volatile("v_pk_min_f16 %0, %1, %2" : "=v"(d) : "v"(a), "v"(b));
    return d;
}
__device__ __forceinline__ unsigned selpair(unsigned mx, unsigned mn, float g0, float g1) {
    unsigned lo = (g0 >= 0.f) ? (mx & 0x0000FFFFu) : (mn & 0x0000FFFFu);
    unsigned hi = (g1 >= 0.f) ? (mx & 0xFFFF0000u) : (mn & 0xFFFF0000u);
    return lo | hi;
}
__device__ __forceinline__ float bcast_lane(float v, int lane) {
    return __int_as_float(__builtin_amdgcn_readlane(__float_as_int(v), lane));
}

// ---------------- mlp1: h = w1 @ x + b1 (fp16 out), per-block stats partials ----------
// grid 512 = B(2) x MT(8 tiles of 32 m) x NT(32 tiles of 128 n), block 256
__global__ void k_mlp1(const float* __restrict__ x, const float* __restrict__ w1,
                       const float* __restrict__ b1, __half* __restrict__ hH,
                       float2* __restrict__ Mp) {
    __shared__ float xs[64 * 128];
    __shared__ float w1t[64 * 32];
    __shared__ float r1[4], r2[4];

    int bx = blockIdx.x;
    int nt = bx & 31, mt = (bx >> 5) & 7, b = bx >> 8;
    int n0 = nt * 128, m0 = mt * 32;
    int t = threadIdx.x;

    {
        int nq = t & 31, ch = t >> 5;
        #pragma unroll
        for (int p = 0; p < 8; p++) {
            int c = p * 8 + ch;
            float4 v = *(const float4*)&x[((size_t)(b * CC + c)) * NN + n0 + nq * 4];
            *(float4*)&xs[c * 128 + nq * 4] = v;
        }
    }
    {
        #pragma unroll
        for (int p = 0; p < 2; p++) {
            int idx = p * 256 + t;
            int m = idx >> 4, cq = idx & 15;
            float4 v = *(const float4*)&w1[(m0 + m) * CC + cq * 4];
            w1t[(cq * 4 + 0) * 32 + m] = v.x;
            w1t[(cq * 4 + 1) * 32 + m] = v.y;
            w1t[(cq * 4 + 2) * 32 + m] = v.z;
            w1t[(cq * 4 + 3) * 32 + m] = v.w;
        }
    }
    __syncthreads();

    int nq = t & 31;
    int mseg = t >> 5;
    float o[4][4];
    #pragma unroll
    for (int i = 0; i < 4; i++)
        #pragma unroll
        for (int j = 0; j < 4; j++) o[i][j] = 0.f;

    for (int c = 0; c < 64; c++) {
        float4 xv = *(float4*)&xs[c * 128 + nq * 4];
        float4 wv = *(float4*)&w1t[c * 32 + mseg * 4];
        o[0][0] = fmaf(wv.x, xv.x, o[0][0]); o[0][1] = fmaf(wv.x, xv.y, o[0][1]);
        o[0][2] = fmaf(wv.x, xv.z, o[0][2]); o[0][3] = fmaf(wv.x, xv.w, o[0][3]);
        o[1][0] = fmaf(wv.y, xv.x, o[1][0]); o[1][1] = fmaf(wv.y, xv.y, o[1][1]);
        o[1][2] = fmaf(wv.y, xv.z, o[1][2]); o[1][3] = fmaf(wv.y, xv.w, o[1][3]);
        o[2][0] = fmaf(wv.z, xv.x, o[2][0]); o[2][1] = fmaf(wv.z, xv.y, o[2][1]);
        o[2][2] = fmaf(wv.z, xv.z, o[2][2]); o[2][3] = fmaf(wv.z, xv.w, o[2][3]);
        o[3][0] = fmaf(wv.w, xv.x, o[3][0]); o[3][1] = fmaf(wv.w, xv.y, o[3][1]);
        o[3][2] = fmaf(wv.w, xv.z, o[3][2]); o[3][3] = fmaf(wv.w, xv.w, o[3][3]);
    }

    float s1 = 0.f, s2 = 0.f;
    #pragma unroll
    for (int mi = 0; mi < 4; mi++) {
        int m = m0 + mseg * 4 + mi;
        float bv = b1[m];
        float4 r;
        r.x = o[mi][0] + bv; r.y = o[mi][1] + bv;
        r.z = o[mi][2] + bv; r.w = o[mi][3] + bv;
        __half2 hA = __float22half2_rn(make_float2(r.x, r.y));
        __half2 hB = __float22half2_rn(make_float2(r.z, r.w));
        uint2 st8;
        st8.x = *(unsigned*)&hA; st8.y = *(unsigned*)&hB;
        *(uint2*)((char*)hH + (((size_t)(b * MM + m)) * NN + n0 + nq * 4) * 2) = st8;
        s1 += r.x + r.y + r.z + r.w;
        s2 = fmaf(r.x, r.x, s2); s2 = fmaf(r.y, r.y, s2);
        s2 = fmaf(r.z, r.z, s2); s2 = fmaf(r.w, r.w, s2);
    }
    for (int off = 32; off; off >>= 1) {
        s1 += __shfl_down(s1, off, 64);
        s2 += __shfl_down(s2, off, 64);
    }
    int w = t >> 6, l = t & 63;
    if (l == 0) { r1[w] = s1; r2[w] = s2; }
    __syncthreads();
    if (t == 0) {
        Mp[bx] = make_float2(r1[0] + r1[1] + r1[2] + r1[3],
                             r2[0] + r2[1] + r2[2] + r2[3]);
    }
}

// ---------------- union kernel: gn1t (blocks 0..511) + ballq (blocks 512..2559) ----------
// Bodies identical to R12 passing versions.
// fma-contraction safety: do NOT rewrite the ballq distance expression tree.
__global__ void k_gn1t_ballq(const __half* __restrict__ hH, const float* __restrict__ g1,
                             const float* __restrict__ be1, const float* __restrict__ wd,
                             const float2* __restrict__ Mp, __half* __restrict__ pH,
                             float* __restrict__ R,
                             const float* __restrict__ pos, int* __restrict__ idx) {
    __shared__ float tile[64 * 65];
    __shared__ float mv[2];
    int t = threadIdx.x;

    if (blockIdx.x < 512) {
        // ---- gn1t body ----
        int id = blockIdx.x;
        int n0 = (id & 63) * 64;
        int g  = (id >> 6) & 3;
        int b  = id >> 8;
        int m0 = g * 64;

        if (t < 64) {
            float2 p2 = Mp[b * 256 + g * 64 + t];
            float s1 = p2.x, s2 = p2.y;
            for (int off = 32; off; off >>= 1) {
                s1 += __shfl_down(s1, off, 64);
                s2 += __shfl_down(s2, off, 64);
            }
            if (t == 0) {
                const double cnt = 64.0 * 4096.0;
                double md = (double)s1 / cnt;
                double vd = (double)s2 / cnt - md * md;
                mv[0] = (float)md;
                mv[1] = rsqrtf((float)vd + EPSF);
            }
        }
        __syncthreads();
        float mean = mv[0], rstd = mv[1];

        int nq = t & 15, mr = t >> 4;
        #pragma unroll
        for (int pp = 0; pp < 4; pp++) {
            int row = pp * 16 + mr;
            int m = m0 + row;
            float a = rstd * g1[m];
            float cc2 = be1[m] - mean * a;
            float wdm = wd[m];
            uint2 raw = *(const uint2*)((const char*)hH +
                         (((size_t)(b * MM + m)) * NN + n0 + nq * 4) * 2);
            float2 fa = __half22float2(*(__half2*)&raw.x);
            float2 fb = __half22float2(*(__half2*)&raw.y);
            tile[row * 65 + nq * 4 + 0] = gelu_exact(fmaf(fa.x, a, cc2)) * wdm;
            tile[row * 65 + nq * 4 + 1] = gelu_exact(fmaf(fa.y, a, cc2)) * wdm;
            tile[row * 65 + nq * 4 + 2] = gelu_exact(fmaf(fb.x, a, cc2)) * wdm;
            tile[row * 65 + nq * 4 + 3] = gelu_exact(fmaf(fb.y, a, cc2)) * wdm;
        }
        __syncthreads();
        #pragma unroll
        for (int pp = 0; pp < 4; pp++) {
            int id2 = pp * 256 + t;
            int nl = id2 >> 4, mq = id2 & 15;
            float a0 = tile[(mq * 4 + 0) * 65 + nl];
            float a1 = tile[(mq * 4 + 1) * 65 + nl];
            float a2 = tile[(mq * 4 + 2) * 65 + nl];
            float a3 = tile[(mq * 4 + 3) * 65 + nl];
            __half2 hA = __float22half2_rn(make_float2(a0, a1));
            __half2 hB = __float22half2_rn(make_float2(a2, a3));
            uint2 st8;
            st8.x = *(unsigned*)&hA; st8.y = *(unsigned*)&hB;
            *(uint2*)((char*)pH + ((((size_t)(b * NN) + n0 + nl)) << 9) + (m0 + mq * 4) * 2) = st8;
            float2 fa = __half22float2(hA);
            float2 fb = __half22float2(hB);
            float t1 = fa.x + fa.y + fb.x + fb.y;
            float t2 = fa.x * fa.x + fa.y * fa.y + fb.x * fb.x + fb.y * fb.y;
            #pragma unroll
            for (int off = 8; off; off >>= 1) {
                t1 += __shfl_down(t1, off, 16);
                t2 += __shfl_down(t2, off, 16);
            }
            if ((t & 15) == 0) {
                float* rr = &R[((size_t)(b * NN) + n0 + nl) * 8];
                rr[g]     = t1;
                rr[4 + g] = t2;
            }
        }
    } else {
        // ---- ballq body (bx = blockIdx.x - 512) ----
        int bx = blockIdx.x - 512;
        int wid  = bx * 4 + (threadIdx.x >> 6);
        int lane = threadIdx.x & 63;
        int b = wid >> 12;
        int n = wid & 4095;
        const float* px = pos + b * 3 * NN;
        const float* py = px + NN;
        const float* pz = py + NN;
        float qx = px[n], qy = py[n], qz = pz[n];
        float qsq = qx*qx + qy*qy + qz*qz;
        int* row = idx + (b * NN + n) * KK;

        int found = 0;
        int first = -1;
        const float R2 = 0.04f;
        for (int m0 = 0; m0 < NN && found < KK; m0 += 64) {
            int m = m0 + lane;
            float ax = px[m], ay = py[m], az = pz[m];
            float msq = ax*ax + ay*ay + az*az;
            float dot = qx*ax + qy*ay + qz*az;
            float d = qsq + msq - 2.0f * dot;
            bool hit = !(d > R2);
            unsigned long long mask = __ballot(hit);
            if (first < 0 && mask) first = m0 + (__ffsll((long long)mask) - 1);
            unsigned long long lt = (lane == 0) ? 0ULL : (mask & ((1ULL << lane) - 1ULL));
            int posh = __popcll(lt);
            if (hit && (found + posh) < KK) row[found + posh] = m;
            found += __popcll(mask);
            if (found > KK) found = KK;
        }
        if (lane < KK && lane >= found) row[lane] = first;
    }
}

// ---------------- union kernel: qgather (blocks 0..2047) + gstats (2048..2303) ----------
// XCD-aware batch split: blocks dispatch round-robin to XCDs (blockIdx % 8), so
// blocks with (q%8)<4 handle batch 0, else batch 1 -> each XCD's L2 caches only
// one batch's 2 MB of pH instead of thrashing the full 4 MB. Pure perf heuristic;
// every point is still covered exactly once; math bodies byte-identical.
__global__ __launch_bounds__(256)
void k_qgather_gstats(const __half* __restrict__ pH, const int* __restrict__ idx,
                      const float* __restrict__ R, const float* __restrict__ gd,
                      __half* __restrict__ pselH, float* __restrict__ Gp) {
    __shared__ float sAcc[8][8];
    int t = threadIdx.x;

    if (blockIdx.x < 2048) {
        int q = blockIdx.x;
        int b = ((q & 7) < 4) ? 0 : 1;
        int local = (q >> 3) * 4 + (q & 3);     // [0, 1024), unique per batch
        int w = t >> 6, l = t & 63;
        int gn = b * NN + local * 4 + w;

        int hh = l >> 5, cl = l & 31;
        int myidx = idx[gn * KK + cl];
        const char* pb = (const char*)(pH + (size_t)b * NN * 256);
        int laneoff = cl * 16;

        unsigned vmax0 = 0xFC00FC00u, vmax1 = 0xFC00FC00u, vmax2 = 0xFC00FC00u, vmax3 = 0xFC00FC00u;
        unsigned vmin0 = 0x7C007C00u, vmin1 = 0x7C007C00u, vmin2 = 0x7C007C00u, vmin3 = 0x7C007C00u;

        #pragma unroll
        for (int k = 0; k < 16; k++) {
            int ja = __shfl(myidx, 2 * k, 64);
            int jb = __shfl(myidx, 2 * k + 1, 64);
            int j = hh ? jb : ja;
            uint4 raw = *(const uint4*)(pb + (((size_t)j) << 9) + laneoff);
            vmax0 = pkmax(vmax0, raw.x); vmin0 = pkmin(vmin0, raw.x);
            vmax1 = pkmax(vmax1, raw.y); vmin1 = pkmin(vmin1, raw.y);
            vmax2 = pkmax(vmax2, raw.z); vmin2 = pkmin(vmin2, raw.z);
            vmax3 = pkmax(vmax3, raw.w); vmin3 = pkmin(vmin3, raw.w);
        }
        vmax0 = pkmax(vmax0, (unsigned)__shfl_xor((int)vmax0, 32, 64));
        vmax1 = pkmax(vmax1, (unsigned)__shfl_xor((int)vmax1, 32, 64));
        vmax2 = pkmax(vmax2, (unsigned)__shfl_xor((int)vmax2, 32, 64));
        vmax3 = pkmax(vmax3, (unsigned)__shfl_xor((int)vmax3, 32, 64));
        vmin0 = pkmin(vmin0, (unsigned)__shfl_xor((int)vmin0, 32, 64));
        vmin1 = pkmin(vmin1, (unsigned)__shfl_xor((int)vmin1, 32, 64));
        vmin2 = pkmin(vmin2, (unsigned)__shfl_xor((int)vmin2, 32, 64));
        vmin3 = pkmin(vmin3, (unsigned)__shfl_xor((int)vmin3, 32, 64));

        if (hh == 0) {
            const float4* g4 = (const float4*)gd;
            float4 gA = g4[cl * 2], gB = g4[cl * 2 + 1];
            uint4 o4;
            o4.x = selpair(vmax0, vmin0, gA.x, gA.y);
            o4.y = selpair(vmax1, vmin1, gA.z, gA.w);
            o4.z = selpair(vmax2, vmin2, gB.x, gB.y);
            o4.w = selpair(vmax3, vmin3, gB.z, gB.w);
            *(uint4*)((char*)pselH + (((size_t)gn) << 9) + laneoff) = o4;
        }
    } else {
        int bid = blockIdx.x - 2048;
        int hw = t >> 5, cl = t & 31;
        int pbase = bid * 32;
        int b = pbase >> 12;
        float s[8];
        #pragma unroll
        for (int c = 0; c < 8; c++) s[c] = 0.f;
        #pragma unroll
        for (int it = 0; it < 4; it++) {
            int pt = pbase + it * 8 + hw;
            int j = idx[pt * KK + cl];
            const float* rr = &R[((size_t)(b * NN) + j) * 8];
            float4 ra = *(const float4*)rr;
            float4 rb = *(const float4*)(rr + 4);
            s[0] += ra.x; s[1] += ra.y; s[2] += ra.z; s[3] += ra.w;
            s[4] += rb.x; s[5] += rb.y; s[6] += rb.z; s[7] += rb.w;
        }
        #pragma unroll
        for (int off = 16; off; off >>= 1) {
            #pragma unroll
            for (int c = 0; c < 8; c++) s[c] += __shfl_down(s[c], off, 32);
        }
        if (cl == 0) {
            #pragma unroll
            for (int c = 0; c < 8; c++) sAcc[hw][c] = s[c];
        }
        __syncthreads();
        if (t < 8) {
            float v = 0.f;
            #pragma unroll
            for (int k = 0; k < 8; k++) v += sAcc[k][t];
            Gp[bid * 8 + t] = v;
        }
    }
}

// ---------------- mlp2: st2 from Gp, h2 = gelu(gn2(sel)), o = w2 @ h2 + b2, Op partials --
// grid 256 blocks, block 256 = 4 waves; lane l owns output channel c = l; wave covers 8 n.
// XCD-aware batch split like qgather; Op row index = b*128+local so k_final's
// layout (128 rows per batch) is unchanged.
__global__ __launch_bounds__(256, 4)
void k_mlp2(const __half* __restrict__ pselH, const float* __restrict__ Gp,
            const float* __restrict__ w2, const float* __restrict__ b2,
            const float* __restrict__ gd, const float* __restrict__ bed,
            float* __restrict__ oraw, float* __restrict__ Op) {
    __shared__ float w2s[64 * 257];
    __shared__ float sw[4][8];
    __shared__ float sA[4][4], sB[4][4];

    int t = threadIdx.x;
    int w = t >> 6, l = t & 63;
    int q = blockIdx.x;
    int b = ((q & 7) < 4) ? 0 : 1;
    int local = (q >> 3) * 4 + (q & 3);        // [0, 128), unique per batch
    int n0 = local * 32 + w * 8;

    #pragma unroll
    for (int p = 0; p < 16; p++) {
        int i = p * 256 + t;
        int c = i >> 6, mq = i & 63;
        float4 v = ((const float4*)w2)[i];
        float* dst = &w2s[c * 257 + mq * 4];
        dst[0] = v.x; dst[1] = v.y; dst[2] = v.z; dst[3] = v.w;
    }

    {
        float s[8] = {0.f, 0.f, 0.f, 0.f, 0.f, 0.f, 0.f, 0.f};
        if (t < 128) {
            const float4* gp = (const float4*)(Gp + ((size_t)(b * 128 + t)) * 8);
            float4 ra = gp[0], rb = gp[1];
            s[0] = ra.x; s[1] = ra.y; s[2] = ra.z; s[3] = ra.w;
            s[4] = rb.x; s[5] = rb.y; s[6] = rb.z; s[7] = rb.w;
        }
        #pragma unroll
        for (int off = 32; off; off >>= 1) {
            #pragma unroll
            for (int c = 0; c < 8; c++) s[c] += __shfl_down(s[c], off, 64);
        }
        if (l == 0) {
            #pragma unroll
            for (int c = 0; c < 8; c++) sw[w][c] = s[c];
        }
    }
    __syncthreads();

    int g = l >> 4;
    double s1 = (double)sw[0][g] + sw[1][g] + sw[2][g] + sw[3][g];
    double s2 = (double)sw[0][4 + g] + sw[1][4 + g] + sw[2][4 + g] + sw[3][4 + g];
    const double cnt2 = 64.0 * 4096.0 * 32.0;
    double m_ = s1 / cnt2;
    double v_ = s2 / cnt2 - m_ * m_;
    float mean = (float)m_;
    float rstd = rsqrtf((float)v_ + EPSF);
    float4 gd4  = ((const float4*)gd)[l];
    float4 bed4 = ((const float4*)bed)[l];
    float ax = rstd * gd4.x, ay = rstd * gd4.y, az = rstd * gd4.z, aw = rstd * gd4.w;
    float cx = bed4.x - mean * ax, cy = bed4.y - mean * ay;
    float cz = bed4.z - mean * az, cw = bed4.w - mean * aw;

    float4 h2r[8];
    #pragma unroll
    for (int j = 0; j < 8; j++) {
        uint2 raw = *(const uint2*)((const char*)pselH +
                     ((((size_t)(b * NN)) + n0 + j) << 9) + l * 8);
        float2 fa = __half22float2(*(__half2*)&raw.x);
        float2 fb = __half22float2(*(__half2*)&raw.y);
        h2r[j].x = gelu_exact(fmaf(fa.x, ax, cx));
        h2r[j].y = gelu_exact(fmaf(fa.y, ay, cy));
        h2r[j].z = gelu_exact(fmaf(fb.x, az, cz));
        h2r[j].w = gelu_exact(fmaf(fb.y, aw, cw));
    }

    const float* w2l = &w2s[l * 257];
    float acc[8];
    #pragma unroll
    for (int j = 0; j < 8; j++) acc[j] = 0.f;

    #pragma unroll 8
    for (int mq = 0; mq < 64; mq++) {
        float w0  = w2l[4 * mq + 0];
        float w1_ = w2l[4 * mq + 1];
        float w2_ = w2l[4 * mq + 2];
        float w3_ = w2l[4 * mq + 3];
        #pragma unroll
        for (int j = 0; j < 8; j++) {
            acc[j] = fmaf(w0,  bcast_lane(h2r[j].x, mq), acc[j]);
            acc[j] = fmaf(w1_, bcast_lane(h2r[j].y, mq), acc[j]);
            acc[j] = fmaf(w2_, bcast_lane(h2r[j].z, mq), acc[j]);
            acc[j] = fmaf(w3_, bcast_lane(h2r[j].w, mq), acc[j]);
        }
    }

    float bias = b2[l];
    float so1 = 0.f, so2 = 0.f;
    #pragma unroll
    for (int j = 0; j < 8; j++) {
        acc[j] += bias;
        so1 += acc[j];
        so2 = fmaf(acc[j], acc[j], so2);
    }
    float* dst = &oraw[((size_t)(b * CC) + l) * NN + n0];
    *(float4*)&dst[0] = make_float4(acc[0], acc[1], acc[2], acc[3]);
    *(float4*)&dst[4] = make_float4(acc[4], acc[5], acc[6], acc[7]);

    so1 += __shfl_down(so1, 8, 16); so2 += __shfl_down(so2, 8, 16);
    so1 += __shfl_down(so1, 4, 16); so2 += __shfl_down(so2, 4, 16);
    so1 += __shfl_down(so1, 2, 16); so2 += __shfl_down(so2, 2, 16);
    so1 += __shfl_down(so1, 1, 16); so2 += __shfl_down(so2, 1, 16);
    if ((l & 15) == 0) { sA[w][l >> 4] = so1; sB[w][l >> 4] = so2; }
    __syncthreads();
    if (t < 8) {
        int is2 = t >> 2, gg = t & 3;
        float v = is2 ? (sB[0][gg] + sB[1][gg] + sB[2][gg] + sB[3][gg])
                      : (sA[0][gg] + sA[1][gg] + sA[2][gg] + sA[3][gg]);
        Op[(b * 128 + local) * 8 + t] = v;   // {s1 g0..3, s2 g0..3}; 128 rows per batch
    }
}

// ---------------- final: st3 from Op (128 rows/batch), gn3 + residual (float4) ----------
// grid 512, block 256
__global__ void k_final(const float* __restrict__ oraw, const float* __restrict__ x,
                        const float* __restrict__ g2, const float* __restrict__ be2,
                        const float* __restrict__ Op, float* __restrict__ out) {
    __shared__ float fw[4][8];
    int t = threadIdx.x;
    int i4 = blockIdx.x * 256 + t;
    int base = i4 * 4;
    int b = base >> 18;

    {
        float s[8] = {0.f, 0.f, 0.f, 0.f, 0.f, 0.f, 0.f, 0.f};
        if (t < 128) {
            const float4* rp = (const float4*)(Op + ((size_t)(b * 128 + t)) * 8);
            float4 ra = rp[0], rb = rp[1];
            s[0] = ra.x; s[1] = ra.y; s[2] = ra.z; s[3] = ra.w;
            s[4] = rb.x; s[5] = rb.y; s[6] = rb.z; s[7] = rb.w;
        }
        #pragma unroll
        for (int off = 32; off; off >>= 1) {
            #pragma unroll
            for (int c = 0; c < 8; c++) s[c] += __shfl_down(s[c], off, 64);
        }
        if ((t & 63) == 0) {
            #pragma unroll
            for (int c = 0; c < 8; c++) fw[t >> 6][c] = s[c];
        }
    }
    __syncthreads();

    int c = (base >> 12) & 63;
    int g = c >> 4;
    double s1 = (double)fw[0][g] + fw[1][g] + fw[2][g] + fw[3][g];
    double s2 = (double)fw[0][4 + g] + fw[1][4 + g] + fw[2][4 + g] + fw[3][4 + g];
    const double cnt = 16.0 * 4096.0;
    double mean_d = s1 / cnt;
    double var_d  = s2 / cnt - mean_d * mean_d;
    float mean = (float)mean_d;
    float rstd = rsqrtf((float)var_d + EPSF);
    float sc = rstd * g2[c];
    float ad = be2[c] - mean * sc;
    float4 o = ((const float4*)oraw)[i4];
    float4 xv = ((const float4*)x)[i4];
    float4 r;
    r.x = fmaf(o.x, sc, ad) + xv.x;
    r.y = fmaf(o.y, sc, ad) + xv.y;
    r.z = fmaf(o.z, sc, ad) + xv.z;
    r.w = fmaf(o.w, sc, ad) + xv.w;
    ((float4*)out)[i4] = r;
}

// ---------------- launch ----------------
extern "C" void kernel_launch(void* const* d_in, const int* in_sizes, int n_in,
                              void* d_out, int out_size, void* d_ws, size_t ws_size,
                              hipStream_t stream) {
    const float* x   = (const float*)d_in[0];
    const float* pos = (const float*)d_in[1];
    const float* w1  = (const float*)d_in[2];
    const float* b1  = (const float*)d_in[3];
    const float* g1  = (const float*)d_in[4];
    const float* be1 = (const float*)d_in[5];
    const float* wd  = (const float*)d_in[6];
    const float* gd  = (const float*)d_in[7];
    const float* bed = (const float*)d_in[8];
    const float* w2  = (const float*)d_in[9];
    const float* b2  = (const float*)d_in[10];
    const float* g2  = (const float*)d_in[11];
    const float* be2 = (const float*)d_in[12];
    float* out = (float*)d_out;

    char* wsb = (char*)d_ws;
    __half* hH    = (__half*)wsb;                    // 4 MB (fp16 h)
    __half* pH    = (__half*)(wsb + 8388608);        // 4 MB
    __half* pselH = (__half*)(wsb + 12582912);       // 4 MB
    float*  oraw  = (float*)(wsb + 16777216);        // 2 MB
    int*    idx   = (int*)(wsb + 18874368);          // 1 MB
    float*  R     = (float*)(wsb + 19922944);        // 256 KB
    float2* Mp    = (float2*)(wsb + 20185088);       // 4 KB
    float*  Gp    = (float*)(wsb + 20189184);        // 8 KB
    float*  Op    = (float*)(wsb + 20197376);        // 8 KB

    k_mlp1<<<512, 256, 0, stream>>>(x, w1, b1, hH, Mp);
    k_gn1t_ballq<<<2560, 256, 0, stream>>>(hH, g1, be1, wd, Mp, pH, R, pos, idx);
    k_qgather_gstats<<<2304, 256, 0, stream>>>(pH, idx, R, gd, pselH, Gp);
    k_mlp2<<<256, 256, 0, stream>>>(pselH, Gp, w2, b2, gd, bed, oraw, Op);
    k_final<<<512, 256, 0, stream>>>(oraw, x, g2, be2, Op, out);
}

// Round 14
// 145.619 us; speedup vs baseline: 1.0189x; 1.0189x over previous
//
#include <hip/hip_runtime.h>
#include <hip/hip_fp16.h>
#include <math.h>

#define BB 2
#define CC 64
#define NN 4096
#define MM 256
#define KK 32
#define GG 4
#define EPSF 1e-5f

__device__ __forceinline__ float gelu_exact(float x) {
    return 0.5f * x * (1.0f + erff(x * 0.70710678118654752f));
}

__device__ __forceinline__ unsigned pkmax(unsigned a, unsigned b) {
    unsigned d;
    asm volatile("v_pk_max_f16 %0, %1, %2" : "=v"(d) : "v"(a), "v"(b));
    return d;
}
__device__ __forceinline__ unsigned pkmin(unsigned a, unsigned b) {
    unsigned d;
    asm volatile("v_pk_min_f16 %0, %1, %2" : "=v"(d) : "v"(a), "v"(b));
    return d;
}
__device__ __forceinline__ unsigned selpair(unsigned mx, unsigned mn, float g0, float g1) {
    unsigned lo = (g0 >= 0.f) ? (mx & 0x0000FFFFu) : (mn & 0x0000FFFFu);
    unsigned hi = (g1 >= 0.f) ? (mx & 0xFFFF0000u) : (mn & 0xFFFF0000u);
    return lo | hi;
}
__device__ __forceinline__ float bcast_lane(float v, int lane) {
    return __int_as_float(__builtin_amdgcn_readlane(__float_as_int(v), lane));
}

// ---------------- mlp1: h = w1 @ x + b1 (fp16 out), per-block stats partials ----------
// grid 512 = B(2) x MT(8 tiles of 32 m) x NT(32 tiles of 128 n), block 256
__global__ void k_mlp1(const float* __restrict__ x, const float* __restrict__ w1,
                       const float* __restrict__ b1, __half* __restrict__ hH,
                       float2* __restrict__ Mp) {
    __shared__ float xs[64 * 128];
    __shared__ float w1t[64 * 32];
    __shared__ float r1[4], r2[4];

    int bx = blockIdx.x;
    int nt = bx & 31, mt = (bx >> 5) & 7, b = bx >> 8;
    int n0 = nt * 128, m0 = mt * 32;
    int t = threadIdx.x;

    {
        int nq = t & 31, ch = t >> 5;
        #pragma unroll
        for (int p = 0; p < 8; p++) {
            int c = p * 8 + ch;
            float4 v = *(const float4*)&x[((size_t)(b * CC + c)) * NN + n0 + nq * 4];
            *(float4*)&xs[c * 128 + nq * 4] = v;
        }
    }
    {
        #pragma unroll
        for (int p = 0; p < 2; p++) {
            int idx = p * 256 + t;
            int m = idx >> 4, cq = idx & 15;
            float4 v = *(const float4*)&w1[(m0 + m) * CC + cq * 4];
            w1t[(cq * 4 + 0) * 32 + m] = v.x;
            w1t[(cq * 4 + 1) * 32 + m] = v.y;
            w1t[(cq * 4 + 2) * 32 + m] = v.z;
            w1t[(cq * 4 + 3) * 32 + m] = v.w;
        }
    }
    __syncthreads();

    int nq = t & 31;
    int mseg = t >> 5;
    float o[4][4];
    #pragma unroll
    for (int i = 0; i < 4; i++)
        #pragma unroll
        for (int j = 0; j < 4; j++) o[i][j] = 0.f;

    for (int c = 0; c < 64; c++) {
        float4 xv = *(float4*)&xs[c * 128 + nq * 4];
        float4 wv = *(float4*)&w1t[c * 32 + mseg * 4];
        o[0][0] = fmaf(wv.x, xv.x, o[0][0]); o[0][1] = fmaf(wv.x, xv.y, o[0][1]);
        o[0][2] = fmaf(wv.x, xv.z, o[0][2]); o[0][3] = fmaf(wv.x, xv.w, o[0][3]);
        o[1][0] = fmaf(wv.y, xv.x, o[1][0]); o[1][1] = fmaf(wv.y, xv.y, o[1][1]);
        o[1][2] = fmaf(wv.y, xv.z, o[1][2]); o[1][3] = fmaf(wv.y, xv.w, o[1][3]);
        o[2][0] = fmaf(wv.z, xv.x, o[2][0]); o[2][1] = fmaf(wv.z, xv.y, o[2][1]);
        o[2][2] = fmaf(wv.z, xv.z, o[2][2]); o[2][3] = fmaf(wv.z, xv.w, o[2][3]);
        o[3][0] = fmaf(wv.w, xv.x, o[3][0]); o[3][1] = fmaf(wv.w, xv.y, o[3][1]);
        o[3][2] = fmaf(wv.w, xv.z, o[3][2]); o[3][3] = fmaf(wv.w, xv.w, o[3][3]);
    }

    float s1 = 0.f, s2 = 0.f;
    #pragma unroll
    for (int mi = 0; mi < 4; mi++) {
        int m = m0 + mseg * 4 + mi;
        float bv = b1[m];
        float4 r;
        r.x = o[mi][0] + bv; r.y = o[mi][1] + bv;
        r.z = o[mi][2] + bv; r.w = o[mi][3] + bv;
        __half2 hA = __float22half2_rn(make_float2(r.x, r.y));
        __half2 hB = __float22half2_rn(make_float2(r.z, r.w));
        uint2 st8;
        st8.x = *(unsigned*)&hA; st8.y = *(unsigned*)&hB;
        *(uint2*)((char*)hH + (((size_t)(b * MM + m)) * NN + n0 + nq * 4) * 2) = st8;
        s1 += r.x + r.y + r.z + r.w;
        s2 = fmaf(r.x, r.x, s2); s2 = fmaf(r.y, r.y, s2);
        s2 = fmaf(r.z, r.z, s2); s2 = fmaf(r.w, r.w, s2);
    }
    for (int off = 32; off; off >>= 1) {
        s1 += __shfl_down(s1, off, 64);
        s2 += __shfl_down(s2, off, 64);
    }
    int w = t >> 6, l = t & 63;
    if (l == 0) { r1[w] = s1; r2[w] = s2; }
    __syncthreads();
    if (t == 0) {
        Mp[bx] = make_float2(r1[0] + r1[1] + r1[2] + r1[3],
                             r2[0] + r2[1] + r2[2] + r2[3]);
    }
}

// ---------------- union kernel: gn1t (blocks 0..511) + ballq (blocks 512..2559) ----------
// Bodies identical to R12/R13 passing versions.
// fma-contraction safety: do NOT rewrite the ballq distance expression tree.
__global__ void k_gn1t_ballq(const __half* __restrict__ hH, const float* __restrict__ g1,
                             const float* __restrict__ be1, const float* __restrict__ wd,
                             const float2* __restrict__ Mp, __half* __restrict__ pH,
                             float* __restrict__ R,
                             const float* __restrict__ pos, int* __restrict__ idx) {
    __shared__ float tile[64 * 65];
    __shared__ float mv[2];
    int t = threadIdx.x;

    if (blockIdx.x < 512) {
        // ---- gn1t body ----
        int id = blockIdx.x;
        int n0 = (id & 63) * 64;
        int g  = (id >> 6) & 3;
        int b  = id >> 8;
        int m0 = g * 64;

        if (t < 64) {
            float2 p2 = Mp[b * 256 + g * 64 + t];
            float s1 = p2.x, s2 = p2.y;
            for (int off = 32; off; off >>= 1) {
                s1 += __shfl_down(s1, off, 64);
                s2 += __shfl_down(s2, off, 64);
            }
            if (t == 0) {
                const double cnt = 64.0 * 4096.0;
                double md = (double)s1 / cnt;
                double vd = (double)s2 / cnt - md * md;
                mv[0] = (float)md;
                mv[1] = rsqrtf((float)vd + EPSF);
            }
        }
        __syncthreads();
        float mean = mv[0], rstd = mv[1];

        int nq = t & 15, mr = t >> 4;
        #pragma unroll
        for (int pp = 0; pp < 4; pp++) {
            int row = pp * 16 + mr;
            int m = m0 + row;
            float a = rstd * g1[m];
            float cc2 = be1[m] - mean * a;
            float wdm = wd[m];
            uint2 raw = *(const uint2*)((const char*)hH +
                         (((size_t)(b * MM + m)) * NN + n0 + nq * 4) * 2);
            float2 fa = __half22float2(*(__half2*)&raw.x);
            float2 fb = __half22float2(*(__half2*)&raw.y);
            tile[row * 65 + nq * 4 + 0] = gelu_exact(fmaf(fa.x, a, cc2)) * wdm;
            tile[row * 65 + nq * 4 + 1] = gelu_exact(fmaf(fa.y, a, cc2)) * wdm;
            tile[row * 65 + nq * 4 + 2] = gelu_exact(fmaf(fb.x, a, cc2)) * wdm;
            tile[row * 65 + nq * 4 + 3] = gelu_exact(fmaf(fb.y, a, cc2)) * wdm;
        }
        __syncthreads();
        #pragma unroll
        for (int pp = 0; pp < 4; pp++) {
            int id2 = pp * 256 + t;
            int nl = id2 >> 4, mq = id2 & 15;
            float a0 = tile[(mq * 4 + 0) * 65 + nl];
            float a1 = tile[(mq * 4 + 1) * 65 + nl];
            float a2 = tile[(mq * 4 + 2) * 65 + nl];
            float a3 = tile[(mq * 4 + 3) * 65 + nl];
            __half2 hA = __float22half2_rn(make_float2(a0, a1));
            __half2 hB = __float22half2_rn(make_float2(a2, a3));
            uint2 st8;
            st8.x = *(unsigned*)&hA; st8.y = *(unsigned*)&hB;
            *(uint2*)((char*)pH + ((((size_t)(b * NN) + n0 + nl)) << 9) + (m0 + mq * 4) * 2) = st8;
            float2 fa = __half22float2(hA);
            float2 fb = __half22float2(hB);
            float t1 = fa.x + fa.y + fb.x + fb.y;
            float t2 = fa.x * fa.x + fa.y * fa.y + fb.x * fb.x + fb.y * fb.y;
            #pragma unroll
            for (int off = 8; off; off >>= 1) {
                t1 += __shfl_down(t1, off, 16);
                t2 += __shfl_down(t2, off, 16);
            }
            if ((t & 15) == 0) {
                float* rr = &R[((size_t)(b * NN) + n0 + nl) * 8];
                rr[g]     = t1;
                rr[4 + g] = t2;
            }
        }
    } else {
        // ---- ballq body (bx = blockIdx.x - 512) ----
        int bx = blockIdx.x - 512;
        int wid  = bx * 4 + (threadIdx.x >> 6);
        int lane = threadIdx.x & 63;
        int b = wid >> 12;
        int n = wid & 4095;
        const float* px = pos + b * 3 * NN;
        const float* py = px + NN;
        const float* pz = py + NN;
        float qx = px[n], qy = py[n], qz = pz[n];
        float qsq = qx*qx + qy*qy + qz*qz;
        int* row = idx + (b * NN + n) * KK;

        int found = 0;
        int first = -1;
        const float R2 = 0.04f;
        for (int m0 = 0; m0 < NN && found < KK; m0 += 64) {
            int m = m0 + lane;
            float ax = px[m], ay = py[m], az = pz[m];
            float msq = ax*ax + ay*ay + az*az;
            float dot = qx*ax + qy*ay + qz*az;
            float d = qsq + msq - 2.0f * dot;
            bool hit = !(d > R2);
            unsigned long long mask = __ballot(hit);
            if (first < 0 && mask) first = m0 + (__ffsll((long long)mask) - 1);
            unsigned long long lt = (lane == 0) ? 0ULL : (mask & ((1ULL << lane) - 1ULL));
            int posh = __popcll(lt);
            if (hit && (found + posh) < KK) row[found + posh] = m;
            found += __popcll(mask);
            if (found > KK) found = KK;
        }
        if (lane < KK && lane >= found) row[lane] = first;
    }
}

// ---------------- union kernel: qgather (blocks 0..2047) + gstats (2048..2303) ----------
// XCD-aware batch split (blockIdx%8 selects batch) so each XCD's L2 caches only
// one batch's 2 MB of pH. Math bodies byte-identical.
__global__ __launch_bounds__(256)
void k_qgather_gstats(const __half* __restrict__ pH, const int* __restrict__ idx,
                      const float* __restrict__ R, const float* __restrict__ gd,
                      __half* __restrict__ pselH, float* __restrict__ Gp) {
    __shared__ float sAcc[8][8];
    int t = threadIdx.x;

    if (blockIdx.x < 2048) {
        int q = blockIdx.x;
        int b = ((q & 7) < 4) ? 0 : 1;
        int local = (q >> 3) * 4 + (q & 3);     // [0, 1024), unique per batch
        int w = t >> 6, l = t & 63;
        int gn = b * NN + local * 4 + w;

        int hh = l >> 5, cl = l & 31;
        int myidx = idx[gn * KK + cl];
        const char* pb = (const char*)(pH + (size_t)b * NN * 256);
        int laneoff = cl * 16;

        unsigned vmax0 = 0xFC00FC00u, vmax1 = 0xFC00FC00u, vmax2 = 0xFC00FC00u, vmax3 = 0xFC00FC00u;
        unsigned vmin0 = 0x7C007C00u, vmin1 = 0x7C007C00u, vmin2 = 0x7C007C00u, vmin3 = 0x7C007C00u;

        #pragma unroll
        for (int k = 0; k < 16; k++) {
            int ja = __shfl(myidx, 2 * k, 64);
            int jb = __shfl(myidx, 2 * k + 1, 64);
            int j = hh ? jb : ja;
            uint4 raw = *(const uint4*)(pb + (((size_t)j) << 9) + laneoff);
            vmax0 = pkmax(vmax0, raw.x); vmin0 = pkmin(vmin0, raw.x);
            vmax1 = pkmax(vmax1, raw.y); vmin1 = pkmin(vmin1, raw.y);
            vmax2 = pkmax(vmax2, raw.z); vmin2 = pkmin(vmin2, raw.z);
            vmax3 = pkmax(vmax3, raw.w); vmin3 = pkmin(vmin3, raw.w);
        }
        vmax0 = pkmax(vmax0, (unsigned)__shfl_xor((int)vmax0, 32, 64));
        vmax1 = pkmax(vmax1, (unsigned)__shfl_xor((int)vmax1, 32, 64));
        vmax2 = pkmax(vmax2, (unsigned)__shfl_xor((int)vmax2, 32, 64));
        vmax3 = pkmax(vmax3, (unsigned)__shfl_xor((int)vmax3, 32, 64));
        vmin0 = pkmin(vmin0, (unsigned)__shfl_xor((int)vmin0, 32, 64));
        vmin1 = pkmin(vmin1, (unsigned)__shfl_xor((int)vmin1, 32, 64));
        vmin2 = pkmin(vmin2, (unsigned)__shfl_xor((int)vmin2, 32, 64));
        vmin3 = pkmin(vmin3, (unsigned)__shfl_xor((int)vmin3, 32, 64));

        if (hh == 0) {
            const float4* g4 = (const float4*)gd;
            float4 gA = g4[cl * 2], gB = g4[cl * 2 + 1];
            uint4 o4;
            o4.x = selpair(vmax0, vmin0, gA.x, gA.y);
            o4.y = selpair(vmax1, vmin1, gA.z, gA.w);
            o4.z = selpair(vmax2, vmin2, gB.x, gB.y);
            o4.w = selpair(vmax3, vmin3, gB.z, gB.w);
            *(uint4*)((char*)pselH + (((size_t)gn) << 9) + laneoff) = o4;
        }
    } else {
        int bid = blockIdx.x - 2048;
        int hw = t >> 5, cl = t & 31;
        int pbase = bid * 32;
        int b = pbase >> 12;
        float s[8];
        #pragma unroll
        for (int c = 0; c < 8; c++) s[c] = 0.f;
        #pragma unroll
        for (int it = 0; it < 4; it++) {
            int pt = pbase + it * 8 + hw;
            int j = idx[pt * KK + cl];
            const float* rr = &R[((size_t)(b * NN) + j) * 8];
            float4 ra = *(const float4*)rr;
            float4 rb = *(const float4*)(rr + 4);
            s[0] += ra.x; s[1] += ra.y; s[2] += ra.z; s[3] += ra.w;
            s[4] += rb.x; s[5] += rb.y; s[6] += rb.z; s[7] += rb.w;
        }
        #pragma unroll
        for (int off = 16; off; off >>= 1) {
            #pragma unroll
            for (int c = 0; c < 8; c++) s[c] += __shfl_down(s[c], off, 32);
        }
        if (cl == 0) {
            #pragma unroll
            for (int c = 0; c < 8; c++) sAcc[hw][c] = s[c];
        }
        __syncthreads();
        if (t < 8) {
            float v = 0.f;
            #pragma unroll
            for (int k = 0; k < 8; k++) v += sAcc[k][t];
            Gp[bid * 8 + t] = v;
        }
    }
}

// ---------------- mlp2: grid 512 (2 blocks/CU), 4 cols/wave; XCD batch split -----------
// Occupancy fix for R13's 42-48 us: 1 block/CU (4 waves) exposed every LDS/dep stall
// (VALUBusy 20%). 512 blocks -> 2/CU -> 8 waves/CU. Op: 256 rows per batch.
__global__ __launch_bounds__(256, 4)
void k_mlp2(const __half* __restrict__ pselH, const float* __restrict__ Gp,
            const float* __restrict__ w2, const float* __restrict__ b2,
            const float* __restrict__ gd, const float* __restrict__ bed,
            float* __restrict__ oraw, float* __restrict__ Op) {
    __shared__ float w2s[64 * 257];
    __shared__ float sw[4][8];
    __shared__ float sA[4][4], sB[4][4];

    int t = threadIdx.x;
    int w = t >> 6, l = t & 63;
    int q = blockIdx.x;
    int b = ((q & 7) < 4) ? 0 : 1;
    int local = (q >> 3) * 4 + (q & 3);        // [0, 256), unique per batch
    int n0 = local * 16 + w * 4;

    #pragma unroll
    for (int p = 0; p < 16; p++) {
        int i = p * 256 + t;
        int c = i >> 6, mq = i & 63;
        float4 v = ((const float4*)w2)[i];
        float* dst = &w2s[c * 257 + mq * 4];
        dst[0] = v.x; dst[1] = v.y; dst[2] = v.z; dst[3] = v.w;
    }

    {
        float s[8] = {0.f, 0.f, 0.f, 0.f, 0.f, 0.f, 0.f, 0.f};
        if (t < 128) {
            const float4* gp = (const float4*)(Gp + ((size_t)(b * 128 + t)) * 8);
            float4 ra = gp[0], rb = gp[1];
            s[0] = ra.x; s[1] = ra.y; s[2] = ra.z; s[3] = ra.w;
            s[4] = rb.x; s[5] = rb.y; s[6] = rb.z; s[7] = rb.w;
        }
        #pragma unroll
        for (int off = 32; off; off >>= 1) {
            #pragma unroll
            for (int c = 0; c < 8; c++) s[c] += __shfl_down(s[c], off, 64);
        }
        if (l == 0) {
            #pragma unroll
            for (int c = 0; c < 8; c++) sw[w][c] = s[c];
        }
    }
    __syncthreads();

    int g = l >> 4;
    double s1 = (double)sw[0][g] + sw[1][g] + sw[2][g] + sw[3][g];
    double s2 = (double)sw[0][4 + g] + sw[1][4 + g] + sw[2][4 + g] + sw[3][4 + g];
    const double cnt2 = 64.0 * 4096.0 * 32.0;
    double m_ = s1 / cnt2;
    double v_ = s2 / cnt2 - m_ * m_;
    float mean = (float)m_;
    float rstd = rsqrtf((float)v_ + EPSF);
    float4 gd4  = ((const float4*)gd)[l];
    float4 bed4 = ((const float4*)bed)[l];
    float ax = rstd * gd4.x, ay = rstd * gd4.y, az = rstd * gd4.z, aw = rstd * gd4.w;
    float cx = bed4.x - mean * ax, cy = bed4.y - mean * ay;
    float cz = bed4.z - mean * az, cw = bed4.w - mean * aw;

    float4 h2r[4];
    #pragma unroll
    for (int j = 0; j < 4; j++) {
        uint2 raw = *(const uint2*)((const char*)pselH +
                     ((((size_t)(b * NN)) + n0 + j) << 9) + l * 8);
        float2 fa = __half22float2(*(__half2*)&raw.x);
        float2 fb = __half22float2(*(__half2*)&raw.y);
        h2r[j].x = gelu_exact(fmaf(fa.x, ax, cx));
        h2r[j].y = gelu_exact(fmaf(fa.y, ay, cy));
        h2r[j].z = gelu_exact(fmaf(fb.x, az, cz));
        h2r[j].w = gelu_exact(fmaf(fb.y, aw, cw));
    }

    const float* w2l = &w2s[l * 257];
    float acc[4] = {0.f, 0.f, 0.f, 0.f};
    #pragma unroll 8
    for (int mq = 0; mq < 64; mq++) {
        float w0  = w2l[4 * mq + 0];
        float w1_ = w2l[4 * mq + 1];
        float w2_ = w2l[4 * mq + 2];
        float w3_ = w2l[4 * mq + 3];
        #pragma unroll
        for (int j = 0; j < 4; j++) {
            acc[j] = fmaf(w0,  bcast_lane(h2r[j].x, mq), acc[j]);
            acc[j] = fmaf(w1_, bcast_lane(h2r[j].y, mq), acc[j]);
            acc[j] = fmaf(w2_, bcast_lane(h2r[j].z, mq), acc[j]);
            acc[j] = fmaf(w3_, bcast_lane(h2r[j].w, mq), acc[j]);
        }
    }

    float bias = b2[l];
    float so1 = 0.f, so2 = 0.f;
    #pragma unroll
    for (int j = 0; j < 4; j++) {
        acc[j] += bias;
        so1 += acc[j];
        so2 = fmaf(acc[j], acc[j], so2);
    }
    *(float4*)&oraw[((size_t)(b * CC) + l) * NN + n0] =
        make_float4(acc[0], acc[1], acc[2], acc[3]);

    so1 += __shfl_down(so1, 8, 16); so2 += __shfl_down(so2, 8, 16);
    so1 += __shfl_down(so1, 4, 16); so2 += __shfl_down(so2, 4, 16);
    so1 += __shfl_down(so1, 2, 16); so2 += __shfl_down(so2, 2, 16);
    so1 += __shfl_down(so1, 1, 16); so2 += __shfl_down(so2, 1, 16);
    if ((l & 15) == 0) { sA[w][l >> 4] = so1; sB[w][l >> 4] = so2; }
    __syncthreads();
    if (t < 8) {
        int is2 = t >> 2, gg = t & 3;
        float v = is2 ? (sB[0][gg] + sB[1][gg] + sB[2][gg] + sB[3][gg])
                      : (sA[0][gg] + sA[1][gg] + sA[2][gg] + sA[3][gg]);
        Op[(b * 256 + local) * 8 + t] = v;   // {s1 g0..3, s2 g0..3}; 256 rows per batch
    }
}

// ---------------- final: st3 from Op (256 rows/batch), gn3 + residual (float4) ----------
// grid 512, block 256
__global__ void k_final(const float* __restrict__ oraw, const float* __restrict__ x,
                        const float* __restrict__ g2, const float* __restrict__ be2,
                        const float* __restrict__ Op, float* __restrict__ out) {
    __shared__ float fw[4][8];
    int t = threadIdx.x;
    int i4 = blockIdx.x * 256 + t;
    int base = i4 * 4;
    int b = base >> 18;

    {
        const float4* rp = (const float4*)(Op + ((size_t)(b * 256 + t)) * 8);
        float4 ra = rp[0], rb = rp[1];
        float s[8] = {ra.x, ra.y, ra.z, ra.w, rb.x, rb.y, rb.z, rb.w};
        #pragma unroll
        for (int off = 32; off; off >>= 1) {
            #pragma unroll
            for (int c = 0; c < 8; c++) s[c] += __shfl_down(s[c], off, 64);
        }
        if ((t & 63) == 0) {
            #pragma unroll
            for (int c = 0; c < 8; c++) fw[t >> 6][c] = s[c];
        }
    }
    __syncthreads();

    int c = (base >> 12) & 63;
    int g = c >> 4;
    double s1 = (double)fw[0][g] + fw[1][g] + fw[2][g] + fw[3][g];
    double s2 = (double)fw[0][4 + g] + fw[1][4 + g] + fw[2][4 + g] + fw[3][4 + g];
    const double cnt = 16.0 * 4096.0;
    double mean_d = s1 / cnt;
    double var_d  = s2 / cnt - mean_d * mean_d;
    float mean = (float)mean_d;
    float rstd = rsqrtf((float)var_d + EPSF);
    float sc = rstd * g2[c];
    float ad = be2[c] - mean * sc;
    float4 o = ((const float4*)oraw)[i4];
    float4 xv = ((const float4*)x)[i4];
    float4 r;
    r.x = fmaf(o.x, sc, ad) + xv.x;
    r.y = fmaf(o.y, sc, ad) + xv.y;
    r.z = fmaf(o.z, sc, ad) + xv.z;
    r.w = fmaf(o.w, sc, ad) + xv.w;
    ((float4*)out)[i4] = r;
}

// ---------------- launch ----------------
extern "C" void kernel_launch(void* const* d_in, const int* in_sizes, int n_in,
                              void* d_out, int out_size, void* d_ws, size_t ws_size,
                              hipStream_t stream) {
    const float* x   = (const float*)d_in[0];
    const float* pos = (const float*)d_in[1];
    const float* w1  = (const float*)d_in[2];
    const float* b1  = (const float*)d_in[3];
    const float* g1  = (const float*)d_in[4];
    const float* be1 = (const float*)d_in[5];
    const float* wd  = (const float*)d_in[6];
    const float* gd  = (const float*)d_in[7];
    const float* bed = (const float*)d_in[8];
    const float* w2  = (const float*)d_in[9];
    const float* b2  = (const float*)d_in[10];
    const float* g2  = (const float*)d_in[11];
    const float* be2 = (const float*)d_in[12];
    float* out = (float*)d_out;

    char* wsb = (char*)d_ws;
    __half* hH    = (__half*)wsb;                    // 4 MB (fp16 h)
    __half* pH    = (__half*)(wsb + 8388608);        // 4 MB
    __half* pselH = (__half*)(wsb + 12582912);       // 4 MB
    float*  oraw  = (float*)(wsb + 16777216);        // 2 MB
    int*    idx   = (int*)(wsb + 18874368);          // 1 MB
    float*  R     = (float*)(wsb + 19922944);        // 256 KB
    float2* Mp    = (float2*)(wsb + 20185088);       // 4 KB
    float*  Gp    = (float*)(wsb + 20189184);        // 8 KB
    float*  Op    = (float*)(wsb + 20197376);        // 16 KB

    k_mlp1<<<512, 256, 0, stream>>>(x, w1, b1, hH, Mp);
    k_gn1t_ballq<<<2560, 256, 0, stream>>>(hH, g1, be1, wd, Mp, pH, R, pos, idx);
    k_qgather_gstats<<<2304, 256, 0, stream>>>(pH, idx, R, gd, pselH, Gp);
    k_mlp2<<<512, 256, 0, stream>>>(pselH, Gp, w2, b2, gd, bed, oraw, Op);
    k_final<<<512, 256, 0, stream>>>(oraw, x, g2, be2, Op, out);
}

// Round 15
// 143.473 us; speedup vs baseline: 1.0341x; 1.0150x over previous
//
#include <hip/hip_runtime.h>
#include <hip/hip_fp16.h>
#include <math.h>

#define BB 2
#define CC 64
#define NN 4096
#define MM 256
#define KK 32
#define GG 4
#define EPSF 1e-5f

__device__ __forceinline__ float gelu_exact(float x) {
    return 0.5f * x * (1.0f + erff(x * 0.70710678118654752f));
}

__device__ __forceinline__ unsigned pkmax(unsigned a, unsigned b) {
    unsigned d;
    asm("v_pk_max_f16 %0, %1, %2" : "=v"(d) : "v"(a), "v"(b));
    return d;
}
__device__ __forceinline__ unsigned pkmin(unsigned a, unsigned b) {
    unsigned d;
    asm("v_pk_min_f16 %0, %1, %2" : "=v"(d) : "v"(a), "v"(b));
    return d;
}
__device__ __forceinline__ unsigned selpair(unsigned mx, unsigned mn, float g0, float g1) {
    unsigned lo = (g0 >= 0.f) ? (mx & 0x0000FFFFu) : (mn & 0x0000FFFFu);
    unsigned hi = (g1 >= 0.f) ? (mx & 0xFFFF0000u) : (mn & 0xFFFF0000u);
    return lo | hi;
}
__device__ __forceinline__ float bcast_lane(float v, int lane) {
    return __int_as_float(__builtin_amdgcn_readlane(__float_as_int(v), lane));
}

// ---------------- mlp1: h = w1 @ x + b1 (fp16 out), per-block stats partials ----------
// grid 512 = B(2) x MT(8 tiles of 32 m) x NT(32 tiles of 128 n), block 256
__global__ void k_mlp1(const float* __restrict__ x, const float* __restrict__ w1,
                       const float* __restrict__ b1, __half* __restrict__ hH,
                       float2* __restrict__ Mp) {
    __shared__ float xs[64 * 128];
    __shared__ float w1t[64 * 32];
    __shared__ float r1[4], r2[4];

    int bx = blockIdx.x;
    int nt = bx & 31, mt = (bx >> 5) & 7, b = bx >> 8;
    int n0 = nt * 128, m0 = mt * 32;
    int t = threadIdx.x;

    {
        int nq = t & 31, ch = t >> 5;
        #pragma unroll
        for (int p = 0; p < 8; p++) {
            int c = p * 8 + ch;
            float4 v = *(const float4*)&x[((size_t)(b * CC + c)) * NN + n0 + nq * 4];
            *(float4*)&xs[c * 128 + nq * 4] = v;
        }
    }
    {
        #pragma unroll
        for (int p = 0; p < 2; p++) {
            int idx = p * 256 + t;
            int m = idx >> 4, cq = idx & 15;
            float4 v = *(const float4*)&w1[(m0 + m) * CC + cq * 4];
            w1t[(cq * 4 + 0) * 32 + m] = v.x;
            w1t[(cq * 4 + 1) * 32 + m] = v.y;
            w1t[(cq * 4 + 2) * 32 + m] = v.z;
            w1t[(cq * 4 + 3) * 32 + m] = v.w;
        }
    }
    __syncthreads();

    int nq = t & 31;
    int mseg = t >> 5;
    float o[4][4];
    #pragma unroll
    for (int i = 0; i < 4; i++)
        #pragma unroll
        for (int j = 0; j < 4; j++) o[i][j] = 0.f;

    for (int c = 0; c < 64; c++) {
        float4 xv = *(float4*)&xs[c * 128 + nq * 4];
        float4 wv = *(float4*)&w1t[c * 32 + mseg * 4];
        o[0][0] = fmaf(wv.x, xv.x, o[0][0]); o[0][1] = fmaf(wv.x, xv.y, o[0][1]);
        o[0][2] = fmaf(wv.x, xv.z, o[0][2]); o[0][3] = fmaf(wv.x, xv.w, o[0][3]);
        o[1][0] = fmaf(wv.y, xv.x, o[1][0]); o[1][1] = fmaf(wv.y, xv.y, o[1][1]);
        o[1][2] = fmaf(wv.y, xv.z, o[1][2]); o[1][3] = fmaf(wv.y, xv.w, o[1][3]);
        o[2][0] = fmaf(wv.z, xv.x, o[2][0]); o[2][1] = fmaf(wv.z, xv.y, o[2][1]);
        o[2][2] = fmaf(wv.z, xv.z, o[2][2]); o[2][3] = fmaf(wv.z, xv.w, o[2][3]);
        o[3][0] = fmaf(wv.w, xv.x, o[3][0]); o[3][1] = fmaf(wv.w, xv.y, o[3][1]);
        o[3][2] = fmaf(wv.w, xv.z, o[3][2]); o[3][3] = fmaf(wv.w, xv.w, o[3][3]);
    }

    float s1 = 0.f, s2 = 0.f;
    #pragma unroll
    for (int mi = 0; mi < 4; mi++) {
        int m = m0 + mseg * 4 + mi;
        float bv = b1[m];
        float4 r;
        r.x = o[mi][0] + bv; r.y = o[mi][1] + bv;
        r.z = o[mi][2] + bv; r.w = o[mi][3] + bv;
        __half2 hA = __float22half2_rn(make_float2(r.x, r.y));
        __half2 hB = __float22half2_rn(make_float2(r.z, r.w));
        uint2 st8;
        st8.x = *(unsigned*)&hA; st8.y = *(unsigned*)&hB;
        *(uint2*)((char*)hH + (((size_t)(b * MM + m)) * NN + n0 + nq * 4) * 2) = st8;
        s1 += r.x + r.y + r.z + r.w;
        s2 = fmaf(r.x, r.x, s2); s2 = fmaf(r.y, r.y, s2);
        s2 = fmaf(r.z, r.z, s2); s2 = fmaf(r.w, r.w, s2);
    }
    for (int off = 32; off; off >>= 1) {
        s1 += __shfl_down(s1, off, 64);
        s2 += __shfl_down(s2, off, 64);
    }
    int w = t >> 6, l = t & 63;
    if (l == 0) { r1[w] = s1; r2[w] = s2; }
    __syncthreads();
    if (t == 0) {
        Mp[bx] = make_float2(r1[0] + r1[1] + r1[2] + r1[3],
                             r2[0] + r2[1] + r2[2] + r2[3]);
    }
}

// ---------------- union kernel: gn1t (blocks 0..511) + ballq (blocks 512..2559) ----------
// Bodies identical to R12/R13/R14 passing versions.
// fma-contraction safety: do NOT rewrite the ballq distance expression tree.
__global__ void k_gn1t_ballq(const __half* __restrict__ hH, const float* __restrict__ g1,
                             const float* __restrict__ be1, const float* __restrict__ wd,
                             const float2* __restrict__ Mp, __half* __restrict__ pH,
                             float* __restrict__ R,
                             const float* __restrict__ pos, int* __restrict__ idx) {
    __shared__ float tile[64 * 65];
    __shared__ float mv[2];
    int t = threadIdx.x;

    if (blockIdx.x < 512) {
        // ---- gn1t body ----
        int id = blockIdx.x;
        int n0 = (id & 63) * 64;
        int g  = (id >> 6) & 3;
        int b  = id >> 8;
        int m0 = g * 64;

        if (t < 64) {
            float2 p2 = Mp[b * 256 + g * 64 + t];
            float s1 = p2.x, s2 = p2.y;
            for (int off = 32; off; off >>= 1) {
                s1 += __shfl_down(s1, off, 64);
                s2 += __shfl_down(s2, off, 64);
            }
            if (t == 0) {
                const double cnt = 64.0 * 4096.0;
                double md = (double)s1 / cnt;
                double vd = (double)s2 / cnt - md * md;
                mv[0] = (float)md;
                mv[1] = rsqrtf((float)vd + EPSF);
            }
        }
        __syncthreads();
        float mean = mv[0], rstd = mv[1];

        int nq = t & 15, mr = t >> 4;
        #pragma unroll
        for (int pp = 0; pp < 4; pp++) {
            int row = pp * 16 + mr;
            int m = m0 + row;
            float a = rstd * g1[m];
            float cc2 = be1[m] - mean * a;
            float wdm = wd[m];
            uint2 raw = *(const uint2*)((const char*)hH +
                         (((size_t)(b * MM + m)) * NN + n0 + nq * 4) * 2);
            float2 fa = __half22float2(*(__half2*)&raw.x);
            float2 fb = __half22float2(*(__half2*)&raw.y);
            tile[row * 65 + nq * 4 + 0] = gelu_exact(fmaf(fa.x, a, cc2)) * wdm;
            tile[row * 65 + nq * 4 + 1] = gelu_exact(fmaf(fa.y, a, cc2)) * wdm;
            tile[row * 65 + nq * 4 + 2] = gelu_exact(fmaf(fb.x, a, cc2)) * wdm;
            tile[row * 65 + nq * 4 + 3] = gelu_exact(fmaf(fb.y, a, cc2)) * wdm;
        }
        __syncthreads();
        #pragma unroll
        for (int pp = 0; pp < 4; pp++) {
            int id2 = pp * 256 + t;
            int nl = id2 >> 4, mq = id2 & 15;
            float a0 = tile[(mq * 4 + 0) * 65 + nl];
            float a1 = tile[(mq * 4 + 1) * 65 + nl];
            float a2 = tile[(mq * 4 + 2) * 65 + nl];
            float a3 = tile[(mq * 4 + 3) * 65 + nl];
            __half2 hA = __float22half2_rn(make_float2(a0, a1));
            __half2 hB = __float22half2_rn(make_float2(a2, a3));
            uint2 st8;
            st8.x = *(unsigned*)&hA; st8.y = *(unsigned*)&hB;
            *(uint2*)((char*)pH + ((((size_t)(b * NN) + n0 + nl)) << 9) + (m0 + mq * 4) * 2) = st8;
            float2 fa = __half22float2(hA);
            float2 fb = __half22float2(hB);
            float t1 = fa.x + fa.y + fb.x + fb.y;
            float t2 = fa.x * fa.x + fa.y * fa.y + fb.x * fb.x + fb.y * fb.y;
            #pragma unroll
            for (int off = 8; off; off >>= 1) {
                t1 += __shfl_down(t1, off, 16);
                t2 += __shfl_down(t2, off, 16);
            }
            if ((t & 15) == 0) {
                float* rr = &R[((size_t)(b * NN) + n0 + nl) * 8];
                rr[g]     = t1;
                rr[4 + g] = t2;
            }
        }
    } else {
        // ---- ballq body (bx = blockIdx.x - 512) ----
        int bx = blockIdx.x - 512;
        int wid  = bx * 4 + (threadIdx.x >> 6);
        int lane = threadIdx.x & 63;
        int b = wid >> 12;
        int n = wid & 4095;
        const float* px = pos + b * 3 * NN;
        const float* py = px + NN;
        const float* pz = py + NN;
        float qx = px[n], qy = py[n], qz = pz[n];
        float qsq = qx*qx + qy*qy + qz*qz;
        int* row = idx + (b * NN + n) * KK;

        int found = 0;
        int first = -1;
        const float R2 = 0.04f;
        for (int m0 = 0; m0 < NN && found < KK; m0 += 64) {
            int m = m0 + lane;
            float ax = px[m], ay = py[m], az = pz[m];
            float msq = ax*ax + ay*ay + az*az;
            float dot = qx*ax + qy*ay + qz*az;
            float d = qsq + msq - 2.0f * dot;
            bool hit = !(d > R2);
            unsigned long long mask = __ballot(hit);
            if (first < 0 && mask) first = m0 + (__ffsll((long long)mask) - 1);
            unsigned long long lt = (lane == 0) ? 0ULL : (mask & ((1ULL << lane) - 1ULL));
            int posh = __popcll(lt);
            if (hit && (found + posh) < KK) row[found + posh] = m;
            found += __popcll(mask);
            if (found > KK) found = KK;
        }
        if (lane < KK && lane >= found) row[lane] = first;
    }
}

// ---------------- union kernel: qgather (blocks 0..2047) + gstats (2048..2303) ----------
// XCD-aware batch split (blockIdx%8 selects batch). Gather loop batched 4 loads at a
// time (explicit uint4 r[4]) for load ILP: R4's VGPR=36 showed only ~2 loads in flight
// -> latency-bound at ~6 TB/s effective. Max/min accumulation is order-independent, so
// the reassociated reduction is bit-exact vs the serial form.
__global__ __launch_bounds__(256)
void k_qgather_gstats(const __half* __restrict__ pH, const int* __restrict__ idx,
                      const float* __restrict__ R, const float* __restrict__ gd,
                      __half* __restrict__ pselH, float* __restrict__ Gp) {
    __shared__ float sAcc[8][8];
    int t = threadIdx.x;

    if (blockIdx.x < 2048) {
        int q = blockIdx.x;
        int b = ((q & 7) < 4) ? 0 : 1;
        int local = (q >> 3) * 4 + (q & 3);     // [0, 1024), unique per batch
        int w = t >> 6, l = t & 63;
        int gn = b * NN + local * 4 + w;

        int hh = l >> 5, cl = l & 31;
        int myidx = idx[gn * KK + cl];
        const char* pb = (const char*)(pH + (size_t)b * NN * 256);
        int laneoff = cl * 16;

        unsigned vmax0 = 0xFC00FC00u, vmax1 = 0xFC00FC00u, vmax2 = 0xFC00FC00u, vmax3 = 0xFC00FC00u;
        unsigned vmin0 = 0x7C007C00u, vmin1 = 0x7C007C00u, vmin2 = 0x7C007C00u, vmin3 = 0x7C007C00u;

        #pragma unroll
        for (int kb = 0; kb < 4; kb++) {
            int jj[4];
            #pragma unroll
            for (int u = 0; u < 4; u++) {
                int k = kb * 4 + u;
                int ja = __shfl(myidx, 2 * k, 64);
                int jb = __shfl(myidx, 2 * k + 1, 64);
                jj[u] = hh ? jb : ja;
            }
            uint4 r[4];
            #pragma unroll
            for (int u = 0; u < 4; u++)
                r[u] = *(const uint4*)(pb + (((size_t)jj[u]) << 9) + laneoff);
            #pragma unroll
            for (int u = 0; u < 4; u++) {
                vmax0 = pkmax(vmax0, r[u].x); vmin0 = pkmin(vmin0, r[u].x);
                vmax1 = pkmax(vmax1, r[u].y); vmin1 = pkmin(vmin1, r[u].y);
                vmax2 = pkmax(vmax2, r[u].z); vmin2 = pkmin(vmin2, r[u].z);
                vmax3 = pkmax(vmax3, r[u].w); vmin3 = pkmin(vmin3, r[u].w);
            }
        }
        vmax0 = pkmax(vmax0, (unsigned)__shfl_xor((int)vmax0, 32, 64));
        vmax1 = pkmax(vmax1, (unsigned)__shfl_xor((int)vmax1, 32, 64));
        vmax2 = pkmax(vmax2, (unsigned)__shfl_xor((int)vmax2, 32, 64));
        vmax3 = pkmax(vmax3, (unsigned)__shfl_xor((int)vmax3, 32, 64));
        vmin0 = pkmin(vmin0, (unsigned)__shfl_xor((int)vmin0, 32, 64));
        vmin1 = pkmin(vmin1, (unsigned)__shfl_xor((int)vmin1, 32, 64));
        vmin2 = pkmin(vmin2, (unsigned)__shfl_xor((int)vmin2, 32, 64));
        vmin3 = pkmin(vmin3, (unsigned)__shfl_xor((int)vmin3, 32, 64));

        if (hh == 0) {
            const float4* g4 = (const float4*)gd;
            float4 gA = g4[cl * 2], gB = g4[cl * 2 + 1];
            uint4 o4;
            o4.x = selpair(vmax0, vmin0, gA.x, gA.y);
            o4.y = selpair(vmax1, vmin1, gA.z, gA.w);
            o4.z = selpair(vmax2, vmin2, gB.x, gB.y);
            o4.w = selpair(vmax3, vmin3, gB.z, gB.w);
            *(uint4*)((char*)pselH + (((size_t)gn) << 9) + laneoff) = o4;
        }
    } else {
        int bid = blockIdx.x - 2048;
        int hw = t >> 5, cl = t & 31;
        int pbase = bid * 32;
        int b = pbase >> 12;
        float s[8];
        #pragma unroll
        for (int c = 0; c < 8; c++) s[c] = 0.f;
        #pragma unroll
        for (int it = 0; it < 4; it++) {
            int pt = pbase + it * 8 + hw;
            int j = idx[pt * KK + cl];
            const float* rr = &R[((size_t)(b * NN) + j) * 8];
            float4 ra = *(const float4*)rr;
            float4 rb = *(const float4*)(rr + 4);
            s[0] += ra.x; s[1] += ra.y; s[2] += ra.z; s[3] += ra.w;
            s[4] += rb.x; s[5] += rb.y; s[6] += rb.z; s[7] += rb.w;
        }
        #pragma unroll
        for (int off = 16; off; off >>= 1) {
            #pragma unroll
            for (int c = 0; c < 8; c++) s[c] += __shfl_down(s[c], off, 32);
        }
        if (cl == 0) {
            #pragma unroll
            for (int c = 0; c < 8; c++) sAcc[hw][c] = s[c];
        }
        __syncthreads();
        if (t < 8) {
            float v = 0.f;
            #pragma unroll
            for (int k = 0; k < 8; k++) v += sAcc[k][t];
            Gp[bid * 8 + t] = v;
        }
    }
}

// ---------------- mlp2: grid 512 (2 blocks/CU), 4 cols/wave; XCD batch split -----------
__global__ __launch_bounds__(256, 4)
void k_mlp2(const __half* __restrict__ pselH, const float* __restrict__ Gp,
            const float* __restrict__ w2, const float* __restrict__ b2,
            const float* __restrict__ gd, const float* __restrict__ bed,
            float* __restrict__ oraw, float* __restrict__ Op) {
    __shared__ float w2s[64 * 257];
    __shared__ float sw[4][8];
    __shared__ float sA[4][4], sB[4][4];

    int t = threadIdx.x;
    int w = t >> 6, l = t & 63;
    int q = blockIdx.x;
    int b = ((q & 7) < 4) ? 0 : 1;
    int local = (q >> 3) * 4 + (q & 3);        // [0, 256), unique per batch
    int n0 = local * 16 + w * 4;

    #pragma unroll
    for (int p = 0; p < 16; p++) {
        int i = p * 256 + t;
        int c = i >> 6, mq = i & 63;
        float4 v = ((const float4*)w2)[i];
        float* dst = &w2s[c * 257 + mq * 4];
        dst[0] = v.x; dst[1] = v.y; dst[2] = v.z; dst[3] = v.w;
    }

    {
        float s[8] = {0.f, 0.f, 0.f, 0.f, 0.f, 0.f, 0.f, 0.f};
        if (t < 128) {
            const float4* gp = (const float4*)(Gp + ((size_t)(b * 128 + t)) * 8);
            float4 ra = gp[0], rb = gp[1];
            s[0] = ra.x; s[1] = ra.y; s[2] = ra.z; s[3] = ra.w;
            s[4] = rb.x; s[5] = rb.y; s[6] = rb.z; s[7] = rb.w;
        }
        #pragma unroll
        for (int off = 32; off; off >>= 1) {
            #pragma unroll
            for (int c = 0; c < 8; c++) s[c] += __shfl_down(s[c], off, 64);
        }
        if (l == 0) {
            #pragma unroll
            for (int c = 0; c < 8; c++) sw[w][c] = s[c];
        }
    }
    __syncthreads();

    int g = l >> 4;
    double s1 = (double)sw[0][g] + sw[1][g] + sw[2][g] + sw[3][g];
    double s2 = (double)sw[0][4 + g] + sw[1][4 + g] + sw[2][4 + g] + sw[3][4 + g];
    const double cnt2 = 64.0 * 4096.0 * 32.0;
    double m_ = s1 / cnt2;
    double v_ = s2 / cnt2 - m_ * m_;
    float mean = (float)m_;
    float rstd = rsqrtf((float)v_ + EPSF);
    float4 gd4  = ((const float4*)gd)[l];
    float4 bed4 = ((const float4*)bed)[l];
    float ax = rstd * gd4.x, ay = rstd * gd4.y, az = rstd * gd4.z, aw = rstd * gd4.w;
    float cx = bed4.x - mean * ax, cy = bed4.y - mean * ay;
    float cz = bed4.z - mean * az, cw = bed4.w - mean * aw;

    float4 h2r[4];
    #pragma unroll
    for (int j = 0; j < 4; j++) {
        uint2 raw = *(const uint2*)((const char*)pselH +
                     ((((size_t)(b * NN)) + n0 + j) << 9) + l * 8);
        float2 fa = __half22float2(*(__half2*)&raw.x);
        float2 fb = __half22float2(*(__half2*)&raw.y);
        h2r[j].x = gelu_exact(fmaf(fa.x, ax, cx));
        h2r[j].y = gelu_exact(fmaf(fa.y, ay, cy));
        h2r[j].z = gelu_exact(fmaf(fb.x, az, cz));
        h2r[j].w = gelu_exact(fmaf(fb.y, aw, cw));
    }

    const float* w2l = &w2s[l * 257];
    float acc[4] = {0.f, 0.f, 0.f, 0.f};
    #pragma unroll 8
    for (int mq = 0; mq < 64; mq++) {
        float w0  = w2l[4 * mq + 0];
        float w1_ = w2l[4 * mq + 1];
        float w2_ = w2l[4 * mq + 2];
        float w3_ = w2l[4 * mq + 3];
        #pragma unroll
        for (int j = 0; j < 4; j++) {
            acc[j] = fmaf(w0,  bcast_lane(h2r[j].x, mq), acc[j]);
            acc[j] = fmaf(w1_, bcast_lane(h2r[j].y, mq), acc[j]);
            acc[j] = fmaf(w2_, bcast_lane(h2r[j].z, mq), acc[j]);
            acc[j] = fmaf(w3_, bcast_lane(h2r[j].w, mq), acc[j]);
        }
    }

    float bias = b2[l];
    float so1 = 0.f, so2 = 0.f;
    #pragma unroll
    for (int j = 0; j < 4; j++) {
        acc[j] += bias;
        so1 += acc[j];
        so2 = fmaf(acc[j], acc[j], so2);
    }
    *(float4*)&oraw[((size_t)(b * CC) + l) * NN + n0] =
        make_float4(acc[0], acc[1], acc[2], acc[3]);

    so1 += __shfl_down(so1, 8, 16); so2 += __shfl_down(so2, 8, 16);
    so1 += __shfl_down(so1, 4, 16); so2 += __shfl_down(so2, 4, 16);
    so1 += __shfl_down(so1, 2, 16); so2 += __shfl_down(so2, 2, 16);
    so1 += __shfl_down(so1, 1, 16); so2 += __shfl_down(so2, 1, 16);
    if ((l & 15) == 0) { sA[w][l >> 4] = so1; sB[w][l >> 4] = so2; }
    __syncthreads();
    if (t < 8) {
        int is2 = t >> 2, gg = t & 3;
        float v = is2 ? (sB[0][gg] + sB[1][gg] + sB[2][gg] + sB[3][gg])
                      : (sA[0][gg] + sA[1][gg] + sA[2][gg] + sA[3][gg]);
        Op[(b * 256 + local) * 8 + t] = v;   // {s1 g0..3, s2 g0..3}; 256 rows per batch
    }
}

// ---------------- final: st3 from Op (256 rows/batch), gn3 + residual (float4) ----------
// grid 512, block 256
__global__ void k_final(const float* __restrict__ oraw, const float* __restrict__ x,
                        const float* __restrict__ g2, const float* __restrict__ be2,
                        const float* __restrict__ Op, float* __restrict__ out) {
    __shared__ float fw[4][8];
    int t = threadIdx.x;
    int i4 = blockIdx.x * 256 + t;
    int base = i4 * 4;
    int b = base >> 18;

    {
        const float4* rp = (const float4*)(Op + ((size_t)(b * 256 + t)) * 8);
        float4 ra = rp[0], rb = rp[1];
        float s[8] = {ra.x, ra.y, ra.z, ra.w, rb.x, rb.y, rb.z, rb.w};
        #pragma unroll
        for (int off = 32; off; off >>= 1) {
            #pragma unroll
            for (int c = 0; c < 8; c++) s[c] += __shfl_down(s[c], off, 64);
        }
        if ((t & 63) == 0) {
            #pragma unroll
            for (int c = 0; c < 8; c++) fw[t >> 6][c] = s[c];
        }
    }
    __syncthreads();

    int c = (base >> 12) & 63;
    int g = c >> 4;
    double s1 = (double)fw[0][g] + fw[1][g] + fw[2][g] + fw[3][g];
    double s2 = (double)fw[0][4 + g] + fw[1][4 + g] + fw[2][4 + g] + fw[3][4 + g];
    const double cnt = 16.0 * 4096.0;
    double mean_d = s1 / cnt;
    double var_d  = s2 / cnt - mean_d * mean_d;
    float mean = (float)mean_d;
    float rstd = rsqrtf((float)var_d + EPSF);
    float sc = rstd * g2[c];
    float ad = be2[c] - mean * sc;
    float4 o = ((const float4*)oraw)[i4];
    float4 xv = ((const float4*)x)[i4];
    float4 r;
    r.x = fmaf(o.x, sc, ad) + xv.x;
    r.y = fmaf(o.y, sc, ad) + xv.y;
    r.z = fmaf(o.z, sc, ad) + xv.z;
    r.w = fmaf(o.w, sc, ad) + xv.w;
    ((float4*)out)[i4] = r;
}

// ---------------- launch ----------------
extern "C" void kernel_launch(void* const* d_in, const int* in_sizes, int n_in,
                              void* d_out, int out_size, void* d_ws, size_t ws_size,
                              hipStream_t stream) {
    const float* x   = (const float*)d_in[0];
    const float* pos = (const float*)d_in[1];
    const float* w1  = (const float*)d_in[2];
    const float* b1  = (const float*)d_in[3];
    const float* g1  = (const float*)d_in[4];
    const float* be1 = (const float*)d_in[5];
    const float* wd  = (const float*)d_in[6];
    const float* gd  = (const float*)d_in[7];
    const float* bed = (const float*)d_in[8];
    const float* w2  = (const float*)d_in[9];
    const float* b2  = (const float*)d_in[10];
    const float* g2  = (const float*)d_in[11];
    const float* be2 = (const float*)d_in[12];
    float* out = (float*)d_out;

    char* wsb = (char*)d_ws;
    __half* hH    = (__half*)wsb;                    // 4 MB (fp16 h)
    __half* pH    = (__half*)(wsb + 8388608);        // 4 MB
    __half* pselH = (__half*)(wsb + 12582912);       // 4 MB
    float*  oraw  = (float*)(wsb + 16777216);        // 2 MB
    int*    idx   = (int*)(wsb + 18874368);          // 1 MB
    float*  R     = (float*)(wsb + 19922944);        // 256 KB
    float2* Mp    = (float2*)(wsb + 20185088);       // 4 KB
    float*  Gp    = (float*)(wsb + 20189184);        // 8 KB
    float*  Op    = (float*)(wsb + 20197376);        // 16 KB

    k_mlp1<<<512, 256, 0, stream>>>(x, w1, b1, hH, Mp);
    k_gn1t_ballq<<<2560, 256, 0, stream>>>(hH, g1, be1, wd, Mp, pH, R, pos, idx);
    k_qgather_gstats<<<2304, 256, 0, stream>>>(pH, idx, R, gd, pselH, Gp);
    k_mlp2<<<512, 256, 0, stream>>>(pselH, Gp, w2, b2, gd, bed, oraw, Op);
    k_final<<<512, 256, 0, stream>>>(oraw, x, g2, be2, Op, out);
}